// Round 6
// baseline (1458.382 us; speedup 1.0000x reference)
//
#include <hip/hip_runtime.h>
#include <hip/hip_bf16.h>
#include <cstdint>
#include <cstddef>

typedef __bf16 bf16_t;
typedef __bf16 bf16x4 __attribute__((ext_vector_type(4)));
typedef __bf16 bf16x8 __attribute__((ext_vector_type(8)));
typedef float f32x4 __attribute__((ext_vector_type(4)));

#define DEV __device__ __forceinline__

// async global->LDS, 16B per lane (wave-uniform LDS base + lane*16)
DEV void async16(const void* g, void* l) {
  __builtin_amdgcn_global_load_lds(
      (const __attribute__((address_space(1))) void*)g,
      (__attribute__((address_space(3))) void*)l, 16, 0, 0);
}

// C[m,n] += scale * sum_{k in chunk z} A[m,k]*B[n,k]  — split-K via blockIdx.z,
// f32 atomicAdd epilogue (C must be pre-zeroed). 128x128 tile, BK=64, 4 waves.
__global__ __launch_bounds__(256) void gemm_bt_sk(
    const bf16_t* __restrict__ A, int lda,
    const bf16_t* __restrict__ B, int ldb,
    float* __restrict__ C, int ldc,
    int Kc, float scale) {
  __shared__ bf16_t As[128 * 64];
  __shared__ bf16_t Bs[128 * 64];

  const int tid = threadIdx.x;
  const int m0 = blockIdx.y * 128;
  const int n0 = blockIdx.x * 128;
  const int kbase = blockIdx.z * Kc;
  const int w = tid >> 6, lane = tid & 63;
  const int wr = w >> 1, wc = w & 1;
  const int lr = lane & 15;
  const int lk8 = (lane >> 4) * 8;

  const bf16_t* ga[4];
  const bf16_t* gb[4];
#pragma unroll
  for (int i = 0; i < 4; ++i) {
    int c = i * 256 + tid;
    int r = c >> 3, col = (c & 7) * 8;
    ga[i] = A + (size_t)(m0 + r) * lda + kbase + col;
    gb[i] = B + (size_t)(n0 + r) * ldb + kbase + col;
  }

  f32x4 acc[4][4] = {};

  for (int k0 = 0; k0 < Kc; k0 += 64) {
    __syncthreads();
#pragma unroll
    for (int i = 0; i < 4; ++i) {
      int c = i * 256 + tid;
      async16(ga[i], &As[c * 8]);
      async16(gb[i], &Bs[c * 8]);
      ga[i] += 64;
      gb[i] += 64;
    }
    __syncthreads();
#pragma unroll
    for (int kk = 0; kk < 2; ++kk) {
      bf16x8 af[4], bfr[4];
#pragma unroll
      for (int m = 0; m < 4; ++m)
        af[m] = *(const bf16x8*)&As[(wr * 64 + m * 16 + lr) * 64 + kk * 32 + lk8];
#pragma unroll
      for (int n = 0; n < 4; ++n)
        bfr[n] = *(const bf16x8*)&Bs[(wc * 64 + n * 16 + lr) * 64 + kk * 32 + lk8];
#pragma unroll
      for (int m = 0; m < 4; ++m)
#pragma unroll
        for (int n = 0; n < 4; ++n)
          acc[m][n] = __builtin_amdgcn_mfma_f32_16x16x32_bf16(af[m], bfr[n],
                                                              acc[m][n], 0, 0, 0);
    }
  }

  // C/D layout: col = lane&15, row = (lane>>4)*4 + j   [m89/m91-verified]
  const int row0 = m0 + wr * 64 + (lane >> 4) * 4;
  const int col0 = n0 + wc * 64 + lr;
#pragma unroll
  for (int m = 0; m < 4; ++m)
#pragma unroll
    for (int n = 0; n < 4; ++n)
#pragma unroll
      for (int j = 0; j < 4; ++j)
        atomicAdd(&C[(size_t)(row0 + m * 16 + j) * ldc + (col0 + n * 16)],
                  acc[m][n][j] * scale);
}

// Fused Q/K/V projections; blockIdx.z in {0,1,2} selects (W,C) pair. bf16 out.
__global__ __launch_bounds__(256) void gemm_qkv(
    const bf16_t* __restrict__ A,
    const bf16_t* W0, const bf16_t* W1, const bf16_t* W2,
    bf16_t* C0, bf16_t* C1, bf16_t* C2) {
  __shared__ bf16_t As[128 * 64];
  __shared__ bf16_t Bs[128 * 64];

  const int z = blockIdx.z;
  const bf16_t* B = (z == 0) ? W0 : (z == 1) ? W1 : W2;
  bf16_t* C = (z == 0) ? C0 : (z == 1) ? C1 : C2;

  const int tid = threadIdx.x;
  const int m0 = blockIdx.y * 128;
  const int n0 = blockIdx.x * 128;
  const int w = tid >> 6, lane = tid & 63;
  const int wr = w >> 1, wc = w & 1;
  const int lr = lane & 15;
  const int lk8 = (lane >> 4) * 8;

  const bf16_t* ga[4];
  const bf16_t* gb[4];
#pragma unroll
  for (int i = 0; i < 4; ++i) {
    int c = i * 256 + tid;
    int r = c >> 3, col = (c & 7) * 8;
    ga[i] = A + (size_t)(m0 + r) * 2048 + col;
    gb[i] = B + (size_t)(n0 + r) * 2048 + col;
  }

  f32x4 acc[4][4] = {};

  for (int k0 = 0; k0 < 2048; k0 += 64) {
    __syncthreads();
#pragma unroll
    for (int i = 0; i < 4; ++i) {
      int c = i * 256 + tid;
      async16(ga[i], &As[c * 8]);
      async16(gb[i], &Bs[c * 8]);
      ga[i] += 64;
      gb[i] += 64;
    }
    __syncthreads();
#pragma unroll
    for (int kk = 0; kk < 2; ++kk) {
      bf16x8 af[4], bfr[4];
#pragma unroll
      for (int m = 0; m < 4; ++m)
        af[m] = *(const bf16x8*)&As[(wr * 64 + m * 16 + lr) * 64 + kk * 32 + lk8];
#pragma unroll
      for (int n = 0; n < 4; ++n)
        bfr[n] = *(const bf16x8*)&Bs[(wc * 64 + n * 16 + lr) * 64 + kk * 32 + lk8];
#pragma unroll
      for (int m = 0; m < 4; ++m)
#pragma unroll
        for (int n = 0; n < 4; ++n)
          acc[m][n] = __builtin_amdgcn_mfma_f32_16x16x32_bf16(af[m], bfr[n],
                                                              acc[m][n], 0, 0, 0);
    }
  }

  const int row0 = m0 + wr * 64 + (lane >> 4) * 4;
  const int col0 = n0 + wc * 64 + lr;
#pragma unroll
  for (int m = 0; m < 4; ++m)
#pragma unroll
    for (int n = 0; n < 4; ++n)
#pragma unroll
      for (int j = 0; j < 4; ++j)
        C[(size_t)(row0 + m * 16 + j) * 2048 + (col0 + n * 16)] =
            (bf16_t)acc[m][n][j];
}

__global__ __launch_bounds__(256) void cast_f32_bf16(
    const float* __restrict__ src, bf16_t* __restrict__ dst, int n4) {
  int i = blockIdx.x * 256 + threadIdx.x;
  if (i >= n4) return;
  float4 v = ((const float4*)src)[i];
  bf16x4 o = {(bf16_t)v.x, (bf16_t)v.y, (bf16_t)v.z, (bf16_t)v.w};
  ((bf16x4*)dst)[i] = o;
}

// src [2048 x 2048] (row r, col d) -> dst[d][dColOff + r] (Vt layout, dLd=4096)
template <typename SrcT>
__global__ __launch_bounds__(256) void transpose_to_vt(
    const SrcT* __restrict__ src, int sLd,
    bf16_t* __restrict__ dst, int dLd, int dColOff) {
  __shared__ bf16_t tile[32][33];
  const int c0 = blockIdx.x * 32;
  const int r0 = blockIdx.y * 32;
  const int tx = threadIdx.x, ty = threadIdx.y;
#pragma unroll
  for (int j = 0; j < 4; ++j) {
    int r = r0 + ty + j * 8;
    tile[ty + j * 8][tx] = (bf16_t)(float)src[(size_t)r * sLd + c0 + tx];
  }
  __syncthreads();
#pragma unroll
  for (int j = 0; j < 4; ++j) {
    int d = c0 + ty + j * 8;
    dst[(size_t)d * dLd + dColOff + r0 + tx] = tile[tx][ty + j * 8];
  }
}

// one block per row of 4096 f32 scores; in-place rewrite as 4096 bf16 probs
__global__ __launch_bounds__(256) void softmax_inplace(float* __restrict__ scores) {
  float* row = scores + (size_t)blockIdx.x * 4096;
  const int t = threadIdx.x;
  const int w = t >> 6, lane = t & 63;
  float4 v[4];
  float mx = -3.0e38f;
#pragma unroll
  for (int i = 0; i < 4; ++i) {
    v[i] = *(const float4*)(row + (size_t)(i * 256 + t) * 4);
    mx = fmaxf(mx, fmaxf(fmaxf(v[i].x, v[i].y), fmaxf(v[i].z, v[i].w)));
  }
#pragma unroll
  for (int o = 32; o > 0; o >>= 1) mx = fmaxf(mx, __shfl_xor(mx, o, 64));
  __shared__ float redm[4], reds[4];
  if (lane == 0) redm[w] = mx;
  __syncthreads();
  mx = fmaxf(fmaxf(redm[0], redm[1]), fmaxf(redm[2], redm[3]));
  const float LOG2E = 1.4426950408889634f;
  float e[16];
  float sum = 0.f;
#pragma unroll
  for (int i = 0; i < 4; ++i) {
    e[i * 4 + 0] = exp2f((v[i].x - mx) * LOG2E);
    e[i * 4 + 1] = exp2f((v[i].y - mx) * LOG2E);
    e[i * 4 + 2] = exp2f((v[i].z - mx) * LOG2E);
    e[i * 4 + 3] = exp2f((v[i].w - mx) * LOG2E);
    sum += e[i * 4] + e[i * 4 + 1] + e[i * 4 + 2] + e[i * 4 + 3];
  }
#pragma unroll
  for (int o = 32; o > 0; o >>= 1) sum += __shfl_xor(sum, o, 64);
  if (lane == 0) reds[w] = sum;
  __syncthreads();
  sum = reds[0] + reds[1] + reds[2] + reds[3];
  float inv = 1.0f / sum;
  bf16_t* orow = (bf16_t*)row;
#pragma unroll
  for (int i = 0; i < 4; ++i) {
    bf16x4 o4 = {(bf16_t)(e[i * 4 + 0] * inv), (bf16_t)(e[i * 4 + 1] * inv),
                 (bf16_t)(e[i * 4 + 2] * inv), (bf16_t)(e[i * 4 + 3] * inv)};
    *(bf16x4*)(orow + (size_t)(i * 256 + t) * 4) = o4;
  }
}

extern "C" void kernel_launch(void* const* d_in, const int* in_sizes, int n_in,
                              void* d_out, int out_size, void* d_ws, size_t ws_size,
                              hipStream_t stream) {
  const float* x = (const float*)d_in[0];
  const float* cK = (const float*)d_in[1];
  const float* cV = (const float*)d_in[2];
  const float* Wq = (const float*)d_in[3];
  const float* Wk = (const float*)d_in[4];
  const float* Wv = (const float*)d_in[5];
  float* out = (float*)d_out;

  // B=4, L=2048, S=2048, D=2048, T=4096 — per-batch processing, 104 MiB ws.
  char* ws = (char*)d_ws;
  bf16_t* wqb  = (bf16_t*)(ws + 0);          //  8,388,608 B
  bf16_t* wkb  = (bf16_t*)(ws + 8388608);
  bf16_t* wvb  = (bf16_t*)(ws + 16777216);
  bf16_t* xb   = (bf16_t*)(ws + 25165824);   //  8,388,608 B  [2048][2048]
  bf16_t* Qb   = (bf16_t*)(ws + 33554432);   //  8,388,608 B  [2048][2048]
  bf16_t* Kcal = (bf16_t*)(ws + 41943040);   // 16,777,216 B  [4096][2048]
  bf16_t* Vt   = (bf16_t*)(ws + 58720256);   // 16,777,216 B  [2048][4096]
  float*  Sc   = (float*)(ws + 75497472);    // 33,554,432 B  [2048][4096] f32
  bf16_t* Vtmp = (bf16_t*)(ws + 75497472);   // aliased: dead before Sc written

  const float inv_scale = 0.022097086912079608f;  // 1/sqrt(2048)
  const size_t MB4 = 4194304;  // elements per [2048][2048] tensor

  // out is atomicAdd-accumulated (split-K PV) -> zero it (harness poisons 0xAA)
  hipMemsetAsync(out, 0, (size_t)out_size * 4, stream);

  // weights once
  cast_f32_bf16<<<4096, 256, 0, stream>>>(Wq, wqb, 1048576);
  cast_f32_bf16<<<4096, 256, 0, stream>>>(Wk, wkb, 1048576);
  cast_f32_bf16<<<4096, 256, 0, stream>>>(Wv, wvb, 1048576);

  for (int b = 0; b < 4; ++b) {
    const float* x_b  = x  + (size_t)b * MB4;
    const float* cK_b = cK + (size_t)b * MB4;
    const float* cV_b = cV + (size_t)b * MB4;
    float* out_b = out + (size_t)b * MB4;

    // prep: x cast; cache_k -> Kcal rows [2048..4096); cache_v -> Vt cols [2048..4096)
    cast_f32_bf16<<<4096, 256, 0, stream>>>(x_b, xb, 1048576);
    cast_f32_bf16<<<4096, 256, 0, stream>>>(cK_b, Kcal + MB4, 1048576);
    transpose_to_vt<float><<<dim3(64, 64, 1), dim3(32, 8), 0, stream>>>(
        cV_b, 2048, Vt, 4096, 2048);

    // fused Q/K/V projections: z selects (W, C)
    gemm_qkv<<<dim3(16, 16, 3), 256, 0, stream>>>(xb, wqb, wkb, wvb,
                                                  Qb, Kcal, Vtmp);
    transpose_to_vt<bf16_t><<<dim3(64, 64, 1), dim3(32, 8), 0, stream>>>(
        Vtmp, 2048, Vt, 4096, 0);

    // scores = inv_scale * Q @ Kcal^T  [2048 x 4096] f32, split-K=2 (1024 blocks)
    hipMemsetAsync(Sc, 0, 33554432, stream);
    gemm_bt_sk<<<dim3(32, 16, 2), 256, 0, stream>>>(
        Qb, 2048, Kcal, 2048, Sc, 4096, 1024, inv_scale);

    // softmax rows, in-place f32 -> bf16 (row stride stays 8192 bf16)
    softmax_inplace<<<2048, 256, 0, stream>>>(Sc);

    // out_b = P @ Vt^T  (k=4096), split-K=4 (1024 blocks), atomic into zeroed out
    gemm_bt_sk<<<dim3(16, 16, 4), 256, 0, stream>>>(
        (const bf16_t*)Sc, 8192, Vt, 4096, out_b, 2048, 1024, 1.0f);
  }
}

// Round 7
// 1278.754 us; speedup vs baseline: 1.1405x; 1.1405x over previous
//
#include <hip/hip_runtime.h>
#include <hip/hip_bf16.h>
#include <cstdint>
#include <cstddef>

typedef __bf16 bf16_t;
typedef __bf16 bf16x4 __attribute__((ext_vector_type(4)));
typedef __bf16 bf16x8 __attribute__((ext_vector_type(8)));
typedef float f32x4 __attribute__((ext_vector_type(4)));

#define DEV __device__ __forceinline__

// async global->LDS, 16B per lane (wave-uniform LDS base + lane*16)
DEV void async16(const void* g, void* l) {
  __builtin_amdgcn_global_load_lds(
      (const __attribute__((address_space(1))) void*)g,
      (__attribute__((address_space(3))) void*)l, 16, 0, 0);
}

// 8-wave (512-thread) 128x128 BT-GEMM: C = scale * sum_k A[m,k]B[n,k], f32 out.
// Waves 4x2 (wr: 4 row-bands of 32, wc: 2 col-bands of 64); per-wave acc[2][4].
// Batched via blockIdx.z with element strides sA/sB/sC.
__global__ __launch_bounds__(512) void gemm_bt8(
    const bf16_t* __restrict__ A, size_t sA, int lda,
    const bf16_t* __restrict__ B, size_t sB, int ldb,
    float* __restrict__ C, size_t sC, int ldc,
    int K, float scale) {
  __shared__ bf16_t As[128 * 64];
  __shared__ bf16_t Bs[128 * 64];

  const int tid = threadIdx.x;
  A += (size_t)blockIdx.z * sA;
  B += (size_t)blockIdx.z * sB;
  C += (size_t)blockIdx.z * sC;
  const int m0 = blockIdx.y * 128, n0 = blockIdx.x * 128;
  const int w = tid >> 6, lane = tid & 63;
  const int wr = w >> 1, wc = w & 1;
  const int lr = lane & 15, lk8 = (lane >> 4) * 8;

  // staging: 1024 chunks of 8 elems per tensor; 512 threads -> 2 each
  const bf16_t* ga[2];
  const bf16_t* gb[2];
#pragma unroll
  for (int i = 0; i < 2; ++i) {
    int c = i * 512 + tid;
    int r = c >> 3, col = (c & 7) * 8;
    ga[i] = A + (size_t)(m0 + r) * lda + col;
    gb[i] = B + (size_t)(n0 + r) * ldb + col;
  }

  f32x4 acc[2][4] = {};

  for (int k0 = 0; k0 < K; k0 += 64) {
    __syncthreads();
#pragma unroll
    for (int i = 0; i < 2; ++i) {
      int c = i * 512 + tid;
      async16(ga[i], &As[c * 8]);
      async16(gb[i], &Bs[c * 8]);
      ga[i] += 64;
      gb[i] += 64;
    }
    __syncthreads();
#pragma unroll
    for (int kk = 0; kk < 2; ++kk) {
      bf16x8 af[2], bfr[4];
#pragma unroll
      for (int m = 0; m < 2; ++m)
        af[m] = *(const bf16x8*)&As[(wr * 32 + m * 16 + lr) * 64 + kk * 32 + lk8];
#pragma unroll
      for (int n = 0; n < 4; ++n)
        bfr[n] = *(const bf16x8*)&Bs[(wc * 64 + n * 16 + lr) * 64 + kk * 32 + lk8];
#pragma unroll
      for (int m = 0; m < 2; ++m)
#pragma unroll
        for (int n = 0; n < 4; ++n)
          acc[m][n] = __builtin_amdgcn_mfma_f32_16x16x32_bf16(af[m], bfr[n],
                                                              acc[m][n], 0, 0, 0);
    }
  }

  // C/D layout: col = lane&15, row = (lane>>4)*4 + j   [m89/m91-verified]
  const int row0 = m0 + wr * 32 + (lane >> 4) * 4;
  const int col0 = n0 + wc * 64 + lr;
#pragma unroll
  for (int m = 0; m < 2; ++m)
#pragma unroll
    for (int n = 0; n < 4; ++n)
#pragma unroll
      for (int j = 0; j < 4; ++j)
        C[(size_t)(row0 + m * 16 + j) * ldc + (col0 + n * 16)] =
            acc[m][n][j] * scale;
}

// 8-wave fused Q/K/V projection; blockIdx.z selects (W, C). bf16 out, K=2048.
// K-output (z==1) remaps global row r -> batch-strided Kcal row:
//   dest elems = (m0>>11)*4194304 extra (no-op when grid.y<=16, i.e. per-batch).
__global__ __launch_bounds__(512) void gemm_qkv8(
    const bf16_t* __restrict__ A,
    const bf16_t* W0, const bf16_t* W1, const bf16_t* W2,
    bf16_t* C0, bf16_t* C1, bf16_t* C2) {
  __shared__ bf16_t As[128 * 64];
  __shared__ bf16_t Bs[128 * 64];

  const int z = blockIdx.z;
  const bf16_t* B = (z == 0) ? W0 : (z == 1) ? W1 : W2;
  bf16_t* C = (z == 0) ? C0 : (z == 1) ? C1 : C2;

  const int tid = threadIdx.x;
  const int m0 = blockIdx.y * 128, n0 = blockIdx.x * 128;
  const size_t cextra = (z == 1) ? (size_t)(m0 >> 11) * 4194304 : 0;
  const int w = tid >> 6, lane = tid & 63;
  const int wr = w >> 1, wc = w & 1;
  const int lr = lane & 15, lk8 = (lane >> 4) * 8;

  const bf16_t* ga[2];
  const bf16_t* gb[2];
#pragma unroll
  for (int i = 0; i < 2; ++i) {
    int c = i * 512 + tid;
    int r = c >> 3, col = (c & 7) * 8;
    ga[i] = A + (size_t)(m0 + r) * 2048 + col;
    gb[i] = B + (size_t)(n0 + r) * 2048 + col;
  }

  f32x4 acc[2][4] = {};

  for (int k0 = 0; k0 < 2048; k0 += 64) {
    __syncthreads();
#pragma unroll
    for (int i = 0; i < 2; ++i) {
      int c = i * 512 + tid;
      async16(ga[i], &As[c * 8]);
      async16(gb[i], &Bs[c * 8]);
      ga[i] += 64;
      gb[i] += 64;
    }
    __syncthreads();
#pragma unroll
    for (int kk = 0; kk < 2; ++kk) {
      bf16x8 af[2], bfr[4];
#pragma unroll
      for (int m = 0; m < 2; ++m)
        af[m] = *(const bf16x8*)&As[(wr * 32 + m * 16 + lr) * 64 + kk * 32 + lk8];
#pragma unroll
      for (int n = 0; n < 4; ++n)
        bfr[n] = *(const bf16x8*)&Bs[(wc * 64 + n * 16 + lr) * 64 + kk * 32 + lk8];
#pragma unroll
      for (int m = 0; m < 2; ++m)
#pragma unroll
        for (int n = 0; n < 4; ++n)
          acc[m][n] = __builtin_amdgcn_mfma_f32_16x16x32_bf16(af[m], bfr[n],
                                                              acc[m][n], 0, 0, 0);
    }
  }

  const int row0 = m0 + wr * 32 + (lane >> 4) * 4;
  const int col0 = n0 + wc * 64 + lr;
#pragma unroll
  for (int m = 0; m < 2; ++m)
#pragma unroll
    for (int n = 0; n < 4; ++n)
#pragma unroll
      for (int j = 0; j < 4; ++j)
        C[cextra + (size_t)(row0 + m * 16 + j) * 2048 + (col0 + n * 16)] =
            (bf16_t)acc[m][n][j];
}

__global__ __launch_bounds__(256) void cast_f32_bf16(
    const float* __restrict__ src, bf16_t* __restrict__ dst, int n4) {
  int i = blockIdx.x * 256 + threadIdx.x;
  if (i >= n4) return;
  float4 v = ((const float4*)src)[i];
  bf16x4 o = {(bf16_t)v.x, (bf16_t)v.y, (bf16_t)v.z, (bf16_t)v.w};
  ((bf16x4*)dst)[i] = o;
}

// all-batch: cache_k [b][s][d] f32 -> Kcal_all[b][2048+s][d] bf16 (pow2 dims)
__global__ __launch_bounds__(256) void cast_prepend_all(
    const float* __restrict__ src, bf16_t* __restrict__ dst) {
  size_t i = (size_t)blockIdx.x * 256 + threadIdx.x;
  size_t e = i * 4;
  size_t b = e >> 22;
  size_t within = e & ((size_t(1) << 22) - 1);
  float4 v = *(const float4*)(src + e);
  bf16x4 o = {(bf16_t)v.x, (bf16_t)v.y, (bf16_t)v.z, (bf16_t)v.w};
  *(bf16x4*)(dst + (b << 23) + (size_t(1) << 22) + within) = o;
}

// src [2048 x 2048] per z (row r, col d) -> dst[d][dColOff + r]; batch strides in elems
template <typename SrcT>
__global__ __launch_bounds__(256) void transpose_to_vt(
    const SrcT* __restrict__ src, size_t sB, int sLd,
    bf16_t* __restrict__ dst, size_t dB, int dLd, int dColOff) {
  __shared__ bf16_t tile[32][33];
  src += (size_t)blockIdx.z * sB;
  dst += (size_t)blockIdx.z * dB;
  const int c0 = blockIdx.x * 32;
  const int r0 = blockIdx.y * 32;
  const int tx = threadIdx.x, ty = threadIdx.y;
#pragma unroll
  for (int j = 0; j < 4; ++j) {
    int r = r0 + ty + j * 8;
    tile[ty + j * 8][tx] = (bf16_t)(float)src[(size_t)r * sLd + c0 + tx];
  }
  __syncthreads();
#pragma unroll
  for (int j = 0; j < 4; ++j) {
    int d = c0 + ty + j * 8;
    dst[(size_t)d * dLd + dColOff + r0 + tx] = tile[tx][ty + j * 8];
  }
}

// one block per row of 4096 f32 scores; in-place rewrite as 4096 bf16 probs
__global__ __launch_bounds__(256) void softmax_inplace(float* __restrict__ scores) {
  float* row = scores + (size_t)blockIdx.x * 4096;
  const int t = threadIdx.x;
  const int w = t >> 6, lane = t & 63;
  float4 v[4];
  float mx = -3.0e38f;
#pragma unroll
  for (int i = 0; i < 4; ++i) {
    v[i] = *(const float4*)(row + (size_t)(i * 256 + t) * 4);
    mx = fmaxf(mx, fmaxf(fmaxf(v[i].x, v[i].y), fmaxf(v[i].z, v[i].w)));
  }
#pragma unroll
  for (int o = 32; o > 0; o >>= 1) mx = fmaxf(mx, __shfl_xor(mx, o, 64));
  __shared__ float redm[4], reds[4];
  if (lane == 0) redm[w] = mx;
  __syncthreads();
  mx = fmaxf(fmaxf(redm[0], redm[1]), fmaxf(redm[2], redm[3]));
  const float LOG2E = 1.4426950408889634f;
  float e[16];
  float sum = 0.f;
#pragma unroll
  for (int i = 0; i < 4; ++i) {
    e[i * 4 + 0] = exp2f((v[i].x - mx) * LOG2E);
    e[i * 4 + 1] = exp2f((v[i].y - mx) * LOG2E);
    e[i * 4 + 2] = exp2f((v[i].z - mx) * LOG2E);
    e[i * 4 + 3] = exp2f((v[i].w - mx) * LOG2E);
    sum += e[i * 4] + e[i * 4 + 1] + e[i * 4 + 2] + e[i * 4 + 3];
  }
#pragma unroll
  for (int o = 32; o > 0; o >>= 1) sum += __shfl_xor(sum, o, 64);
  if (lane == 0) reds[w] = sum;
  __syncthreads();
  sum = reds[0] + reds[1] + reds[2] + reds[3];
  float inv = 1.0f / sum;
  bf16_t* orow = (bf16_t*)row;
#pragma unroll
  for (int i = 0; i < 4; ++i) {
    bf16x4 o4 = {(bf16_t)(e[i * 4 + 0] * inv), (bf16_t)(e[i * 4 + 1] * inv),
                 (bf16_t)(e[i * 4 + 2] * inv), (bf16_t)(e[i * 4 + 3] * inv)};
    *(bf16x4*)(orow + (size_t)(i * 256 + t) * 4) = o4;
  }
}

extern "C" void kernel_launch(void* const* d_in, const int* in_sizes, int n_in,
                              void* d_out, int out_size, void* d_ws, size_t ws_size,
                              hipStream_t stream) {
  const float* x = (const float*)d_in[0];
  const float* cK = (const float*)d_in[1];
  const float* cV = (const float*)d_in[2];
  const float* Wq = (const float*)d_in[3];
  const float* Wk = (const float*)d_in[4];
  const float* Wv = (const float*)d_in[5];
  float* out = (float*)d_out;

  const float inv_scale = 0.022097086912079608f;  // 1/sqrt(2048)
  const size_t MB4 = 4194304;  // elems per [2048][2048]
  char* ws = (char*)d_ws;

  // ws-size tiers (ws_size constant across calls -> graph-capture safe):
  //   A2 >= 293,601,280 : all-batch qkv, PAIR=2 scores/PV
  //   A1 >= 260,046,848 : all-batch qkv, PAIR=1
  //   B  otherwise      : per-batch everything (proven 104 MiB layout)
  const int tier = (ws_size >= 293601280ULL) ? 2
                 : (ws_size >= 260046848ULL) ? 1 : 0;

  bf16_t* wqb = (bf16_t*)(ws + 0);
  bf16_t* wkb = (bf16_t*)(ws + 8388608);
  bf16_t* wvb = (bf16_t*)(ws + 16777216);
  cast_f32_bf16<<<4096, 256, 0, stream>>>(Wq, wqb, 1048576);
  cast_f32_bf16<<<4096, 256, 0, stream>>>(Wk, wkb, 1048576);
  cast_f32_bf16<<<4096, 256, 0, stream>>>(Wv, wvb, 1048576);

  if (tier > 0) {
    // ---- Tier A: all-batch projections ----
    bf16_t* xb   = (bf16_t*)(ws + 25165824);    // [8192][2048]
    bf16_t* Qb   = (bf16_t*)(ws + 58720256);    // [4][2048][2048]
    bf16_t* Kcal = (bf16_t*)(ws + 92274688);    // [4][4096][2048]
    bf16_t* Vt   = (bf16_t*)(ws + 159383552);   // [4][2048][4096]
    float*  Sc   = (float*)(ws + 226492416);    // PAIR x [2048][4096] f32
    bf16_t* Vtmp = (tier == 2) ? (bf16_t*)(ws + 260046848)   // above Sc pair-half
                               : (bf16_t*)(ws + 226492416);  // aliases Sc (dead early)
    const int PAIR = (tier == 2) ? 2 : 1;

    cast_f32_bf16<<<16384, 256, 0, stream>>>(x, xb, 4194304);
    cast_prepend_all<<<16384, 256, 0, stream>>>(cK, Kcal);
    transpose_to_vt<float><<<dim3(64, 64, 4), dim3(32, 8), 0, stream>>>(
        cV, MB4, 2048, Vt, 8388608ULL, 4096, 2048);

    gemm_qkv8<<<dim3(16, 64, 3), 512, 0, stream>>>(xb, wqb, wkb, wvb,
                                                   Qb, Kcal, Vtmp);
    transpose_to_vt<bf16_t><<<dim3(64, 64, 4), dim3(32, 8), 0, stream>>>(
        Vtmp, MB4, 2048, Vt, 8388608ULL, 4096, 0);

    for (int bp = 0; bp < 4; bp += PAIR) {
      gemm_bt8<<<dim3(32, 16, PAIR), 512, 0, stream>>>(
          Qb + (size_t)bp * MB4, MB4, 2048,
          Kcal + (size_t)bp * 8388608, 8388608ULL, 2048,
          Sc, 8388608ULL, 4096, 2048, inv_scale);
      softmax_inplace<<<2048 * PAIR, 256, 0, stream>>>(Sc);
      gemm_bt8<<<dim3(16, 16, PAIR), 512, 0, stream>>>(
          (const bf16_t*)Sc, 16777216ULL, 8192,
          Vt + (size_t)bp * 8388608, 8388608ULL, 4096,
          out + (size_t)bp * MB4, MB4, 2048, 4096, 1.0f);
    }
  } else {
    // ---- Tier B: per-batch (104 MiB) ----
    bf16_t* xb   = (bf16_t*)(ws + 25165824);   // [2048][2048]
    bf16_t* Qb   = (bf16_t*)(ws + 33554432);   // [2048][2048]
    bf16_t* Kcal = (bf16_t*)(ws + 41943040);   // [4096][2048]
    bf16_t* Vt   = (bf16_t*)(ws + 58720256);   // [2048][4096]
    float*  Sc   = (float*)(ws + 75497472);    // [2048][4096] f32
    bf16_t* Vtmp = (bf16_t*)(ws + 75497472);   // aliases Sc (dead before Sc)

    for (int b = 0; b < 4; ++b) {
      const float* x_b  = x  + (size_t)b * MB4;
      const float* cK_b = cK + (size_t)b * MB4;
      const float* cV_b = cV + (size_t)b * MB4;
      float* out_b = out + (size_t)b * MB4;

      cast_f32_bf16<<<4096, 256, 0, stream>>>(x_b, xb, 1048576);
      cast_f32_bf16<<<4096, 256, 0, stream>>>(cK_b, Kcal + MB4, 1048576);
      transpose_to_vt<float><<<dim3(64, 64, 1), dim3(32, 8), 0, stream>>>(
          cV_b, 0, 2048, Vt, 0, 4096, 2048);

      gemm_qkv8<<<dim3(16, 16, 3), 512, 0, stream>>>(xb, wqb, wkb, wvb,
                                                     Qb, Kcal, Vtmp);
      transpose_to_vt<bf16_t><<<dim3(64, 64, 1), dim3(32, 8), 0, stream>>>(
          Vtmp, 0, 2048, Vt, 0, 4096, 0);

      gemm_bt8<<<dim3(32, 16, 1), 512, 0, stream>>>(
          Qb, 0, 2048, Kcal, 0, 2048, Sc, 0, 4096, 2048, inv_scale);
      softmax_inplace<<<2048, 256, 0, stream>>>(Sc);
      gemm_bt8<<<dim3(16, 16, 1), 512, 0, stream>>>(
          (const bf16_t*)Sc, 0, 8192, Vt, 0, 4096, out_b, 0, 2048, 4096, 1.0f);
    }
  }
}

// Round 10
// 1062.110 us; speedup vs baseline: 1.3731x; 1.2040x over previous
//
#include <hip/hip_runtime.h>
#include <hip/hip_bf16.h>
#include <cstdint>
#include <cstddef>

typedef __bf16 bf16_t;
typedef __bf16 bf16x4 __attribute__((ext_vector_type(4)));
typedef __bf16 bf16x8 __attribute__((ext_vector_type(8)));
typedef float f32x4 __attribute__((ext_vector_type(4)));

#define DEV __device__ __forceinline__

// async global->LDS, 16B per lane (wave-uniform LDS base + lane*16)
DEV void async16(const void* g, void* l) {
  __builtin_amdgcn_global_load_lds(
      (const __attribute__((address_space(1))) void*)g,
      (__attribute__((address_space(3))) void*)l, 16, 0, 0);
}

// m97-geometry BT-GEMM: C = scale * sum_k A[m,k]*B[n,k], f32 out.
// 128x128 tile, BK=64, 4 waves (2x2), per-wave 64x64 = 4x4 mfma_16x16x32.
// Batched via blockIdx.z with element strides sA/sB/sC.
__global__ __launch_bounds__(256) void gemm_bt4(
    const bf16_t* __restrict__ A, size_t sA, int lda,
    const bf16_t* __restrict__ B, size_t sB, int ldb,
    float* __restrict__ C, size_t sC, int ldc,
    int K, float scale) {
  __shared__ bf16_t As[128 * 64];
  __shared__ bf16_t Bs[128 * 64];

  const int tid = threadIdx.x;
  A += (size_t)blockIdx.z * sA;
  B += (size_t)blockIdx.z * sB;
  C += (size_t)blockIdx.z * sC;
  const int m0 = blockIdx.y * 128, n0 = blockIdx.x * 128;
  const int w = tid >> 6, lane = tid & 63;
  const int wr = w >> 1, wc = w & 1;
  const int lr = lane & 15, lk8 = (lane >> 4) * 8;

  const bf16_t* ga[4];
  const bf16_t* gb[4];
#pragma unroll
  for (int i = 0; i < 4; ++i) {
    int c = i * 256 + tid;
    int r = c >> 3, col = (c & 7) * 8;
    ga[i] = A + (size_t)(m0 + r) * lda + col;
    gb[i] = B + (size_t)(n0 + r) * ldb + col;
  }

  f32x4 acc[4][4] = {};

  for (int k0 = 0; k0 < K; k0 += 64) {
    __syncthreads();
#pragma unroll
    for (int i = 0; i < 4; ++i) {
      int c = i * 256 + tid;
      async16(ga[i], &As[c * 8]);
      async16(gb[i], &Bs[c * 8]);
      ga[i] += 64;
      gb[i] += 64;
    }
    __syncthreads();
#pragma unroll
    for (int kk = 0; kk < 2; ++kk) {
      bf16x8 af[4], bfr[4];
#pragma unroll
      for (int m = 0; m < 4; ++m)
        af[m] = *(const bf16x8*)&As[(wr * 64 + m * 16 + lr) * 64 + kk * 32 + lk8];
#pragma unroll
      for (int n = 0; n < 4; ++n)
        bfr[n] = *(const bf16x8*)&Bs[(wc * 64 + n * 16 + lr) * 64 + kk * 32 + lk8];
#pragma unroll
      for (int m = 0; m < 4; ++m)
#pragma unroll
        for (int n = 0; n < 4; ++n)
          acc[m][n] = __builtin_amdgcn_mfma_f32_16x16x32_bf16(af[m], bfr[n],
                                                              acc[m][n], 0, 0, 0);
    }
  }

  // C/D layout: col = lane&15, row = (lane>>4)*4 + j   [m89/m91-verified]
  const int row0 = m0 + wr * 64 + (lane >> 4) * 4;
  const int col0 = n0 + wc * 64 + lr;
#pragma unroll
  for (int m = 0; m < 4; ++m)
#pragma unroll
    for (int n = 0; n < 4; ++n)
#pragma unroll
      for (int j = 0; j < 4; ++j)
        C[(size_t)(row0 + m * 16 + j) * ldc + (col0 + n * 16)] =
            acc[m][n][j] * scale;
}

// Fused Q/K/V projection (m97 geometry), all-batch rows M=8192, K=2048.
// z=0: Q -> Qb[row][col] (linear, batches contiguous)
// z=1: K -> Kcal[b][row%2048][col], b = row>>11 (batch stride 8,388,608 elems)
// z=2: V -> TRANSPOSED into Vt[b][d][l], d=feature, l=row%2048 (stride 4096)
__global__ __launch_bounds__(256) void gemm_qkv4(
    const bf16_t* __restrict__ A,
    const bf16_t* W0, const bf16_t* W1, const bf16_t* W2,
    bf16_t* C0, bf16_t* C1, bf16_t* C2) {
  __shared__ bf16_t As[128 * 64];
  __shared__ bf16_t Bs[128 * 64];

  const int z = blockIdx.z;
  const bf16_t* B = (z == 0) ? W0 : (z == 1) ? W1 : W2;

  const int tid = threadIdx.x;
  const int m0 = blockIdx.y * 128, n0 = blockIdx.x * 128;
  const int w = tid >> 6, lane = tid & 63;
  const int wr = w >> 1, wc = w & 1;
  const int lr = lane & 15, lk8 = (lane >> 4) * 8;

  const bf16_t* ga[4];
  const bf16_t* gb[4];
#pragma unroll
  for (int i = 0; i < 4; ++i) {
    int c = i * 256 + tid;
    int r = c >> 3, col = (c & 7) * 8;
    ga[i] = A + (size_t)(m0 + r) * 2048 + col;
    gb[i] = B + (size_t)(n0 + r) * 2048 + col;
  }

  f32x4 acc[4][4] = {};

  for (int k0 = 0; k0 < 2048; k0 += 64) {
    __syncthreads();
#pragma unroll
    for (int i = 0; i < 4; ++i) {
      int c = i * 256 + tid;
      async16(ga[i], &As[c * 8]);
      async16(gb[i], &Bs[c * 8]);
      ga[i] += 64;
      gb[i] += 64;
    }
    __syncthreads();
#pragma unroll
    for (int kk = 0; kk < 2; ++kk) {
      bf16x8 af[4], bfr[4];
#pragma unroll
      for (int m = 0; m < 4; ++m)
        af[m] = *(const bf16x8*)&As[(wr * 64 + m * 16 + lr) * 64 + kk * 32 + lk8];
#pragma unroll
      for (int n = 0; n < 4; ++n)
        bfr[n] = *(const bf16x8*)&Bs[(wc * 64 + n * 16 + lr) * 64 + kk * 32 + lk8];
#pragma unroll
      for (int m = 0; m < 4; ++m)
#pragma unroll
        for (int n = 0; n < 4; ++n)
          acc[m][n] = __builtin_amdgcn_mfma_f32_16x16x32_bf16(af[m], bfr[n],
                                                              acc[m][n], 0, 0, 0);
    }
  }

  const int row0 = m0 + wr * 64 + (lane >> 4) * 4;
  const int col0 = n0 + wc * 64 + lr;

  if (z == 2) {
    // transposed V store: Vt[b][d][l] ; per (m,n) one bf16x4 (4 consecutive l)
    const size_t bb = (size_t)(m0 >> 11) * 8388608;
    const int l0 = (row0 & 2047);
#pragma unroll
    for (int m = 0; m < 4; ++m)
#pragma unroll
      for (int n = 0; n < 4; ++n) {
        int d = col0 + n * 16;
        bf16x4 o4 = {(bf16_t)acc[m][n][0], (bf16_t)acc[m][n][1],
                     (bf16_t)acc[m][n][2], (bf16_t)acc[m][n][3]};
        *(bf16x4*)&C2[bb + (size_t)d * 4096 + l0 + m * 16] = o4;
      }
  } else {
    bf16_t* C = (z == 0) ? C0 : C1;
    const size_t cextra = (z == 1) ? (size_t)(m0 >> 11) * 4194304 : 0;
#pragma unroll
    for (int m = 0; m < 4; ++m)
#pragma unroll
      for (int n = 0; n < 4; ++n)
#pragma unroll
        for (int j = 0; j < 4; ++j)
          C[cextra + (size_t)(row0 + m * 16 + j) * 2048 + (col0 + n * 16)] =
              (bf16_t)acc[m][n][j];
  }
}

__global__ __launch_bounds__(256) void cast_f32_bf16(
    const float* __restrict__ src, bf16_t* __restrict__ dst, int n4) {
  int i = blockIdx.x * 256 + threadIdx.x;
  if (i >= n4) return;
  float4 v = ((const float4*)src)[i];
  bf16x4 o = {(bf16_t)v.x, (bf16_t)v.y, (bf16_t)v.z, (bf16_t)v.w};
  ((bf16x4*)dst)[i] = o;
}

// all-batch: cache_k [b][s][d] f32 -> Kcal[b][2048+s][d] bf16 (pow2 dims)
__global__ __launch_bounds__(256) void cast_prepend_all(
    const float* __restrict__ src, bf16_t* __restrict__ dst) {
  size_t i = (size_t)blockIdx.x * 256 + threadIdx.x;
  size_t e = i * 4;
  size_t b = e >> 22;
  size_t within = e & ((size_t(1) << 22) - 1);
  float4 v = *(const float4*)(src + e);
  bf16x4 o = {(bf16_t)v.x, (bf16_t)v.y, (bf16_t)v.z, (bf16_t)v.w};
  *(bf16x4*)(dst + (b << 23) + (size_t(1) << 22) + within) = o;
}

// src [2048 x 2048] per z (row r, col d) -> dst[d][dColOff + r]; strides in elems
__global__ __launch_bounds__(256) void transpose_f32_to_vt(
    const float* __restrict__ src, size_t sB, bf16_t* __restrict__ dst,
    size_t dB, int dColOff) {
  __shared__ bf16_t tile[32][33];
  src += (size_t)blockIdx.z * sB;
  dst += (size_t)blockIdx.z * dB;
  const int c0 = blockIdx.x * 32;
  const int r0 = blockIdx.y * 32;
  const int tx = threadIdx.x, ty = threadIdx.y;
#pragma unroll
  for (int j = 0; j < 4; ++j) {
    int r = r0 + ty + j * 8;
    tile[ty + j * 8][tx] = (bf16_t)src[(size_t)r * 2048 + c0 + tx];
  }
  __syncthreads();
#pragma unroll
  for (int j = 0; j < 4; ++j) {
    int d = c0 + ty + j * 8;
    dst[(size_t)d * 4096 + dColOff + r0 + tx] = tile[tx][ty + j * 8];
  }
}

// one block per row: softmax over 4096 f32 -> 4096 bf16 (separate dst)
__global__ __launch_bounds__(256) void softmax_out(
    const float* __restrict__ src, bf16_t* __restrict__ dst) {
  const float* row = src + (size_t)blockIdx.x * 4096;
  bf16_t* orow = dst + (size_t)blockIdx.x * 4096;
  const int t = threadIdx.x;
  const int w = t >> 6, lane = t & 63;
  float4 v[4];
  float mx = -3.0e38f;
#pragma unroll
  for (int i = 0; i < 4; ++i) {
    v[i] = *(const float4*)(row + (size_t)(i * 256 + t) * 4);
    mx = fmaxf(mx, fmaxf(fmaxf(v[i].x, v[i].y), fmaxf(v[i].z, v[i].w)));
  }
#pragma unroll
  for (int o = 32; o > 0; o >>= 1) mx = fmaxf(mx, __shfl_xor(mx, o, 64));
  __shared__ float redm[4], reds[4];
  if (lane == 0) redm[w] = mx;
  __syncthreads();
  mx = fmaxf(fmaxf(redm[0], redm[1]), fmaxf(redm[2], redm[3]));
  const float LOG2E = 1.4426950408889634f;
  float e[16];
  float sum = 0.f;
#pragma unroll
  for (int i = 0; i < 4; ++i) {
    e[i * 4 + 0] = exp2f((v[i].x - mx) * LOG2E);
    e[i * 4 + 1] = exp2f((v[i].y - mx) * LOG2E);
    e[i * 4 + 2] = exp2f((v[i].z - mx) * LOG2E);
    e[i * 4 + 3] = exp2f((v[i].w - mx) * LOG2E);
    sum += e[i * 4] + e[i * 4 + 1] + e[i * 4 + 2] + e[i * 4 + 3];
  }
#pragma unroll
  for (int o = 32; o > 0; o >>= 1) sum += __shfl_xor(sum, o, 64);
  if (lane == 0) reds[w] = sum;
  __syncthreads();
  sum = reds[0] + reds[1] + reds[2] + reds[3];
  float inv = 1.0f / sum;
#pragma unroll
  for (int i = 0; i < 4; ++i) {
    bf16x4 o4 = {(bf16_t)(e[i * 4 + 0] * inv), (bf16_t)(e[i * 4 + 1] * inv),
                 (bf16_t)(e[i * 4 + 2] * inv), (bf16_t)(e[i * 4 + 3] * inv)};
    *(bf16x4*)(orow + (size_t)(i * 256 + t) * 4) = o4;
  }
}

extern "C" void kernel_launch(void* const* d_in, const int* in_sizes, int n_in,
                              void* d_out, int out_size, void* d_ws, size_t ws_size,
                              hipStream_t stream) {
  const float* x = (const float*)d_in[0];
  const float* cK = (const float*)d_in[1];
  const float* cV = (const float*)d_in[2];
  const float* Wq = (const float*)d_in[3];
  const float* Wk = (const float*)d_in[4];
  const float* Wv = (const float*)d_in[5];
  float* out = (float*)d_out;

  const float inv_scale = 0.022097086912079608f;  // 1/sqrt(2048)
  const size_t MB4 = 4194304;  // elems per [2048][2048]
  char* ws = (char*)d_ws;

  // Layout (260,046,848 B total; r7 proved ws_size >= this):
  //   wq/wk/wv  @ 0        : 3 x 8 MiB
  //   xb        @ 25165824 : 32 MiB  [8192][2048] bf16
  //   Qb        @ 58720256 : 32 MiB  [4][2048][2048] bf16
  //   Kcal      @ 92274688 : 64 MiB  [4][4096][2048] bf16
  //   Vt        @159383552 : 64 MiB  [4][2048][4096] bf16
  //   Sc        @226492416 : PAIR x 32 MiB [2048][4096] f32
  //   Pb        @ 25165824 : [4][2048][4096] bf16 (64 MiB) ALIASES xb+Qb —
  //     Pb[b] written by softmax(b); xb dead after qkv, Qb[b] dead after
  //     scores(b), and scores run in batch order, so no overlap hazard.
  bf16_t* wqb  = (bf16_t*)(ws + 0);
  bf16_t* wkb  = (bf16_t*)(ws + 8388608);
  bf16_t* wvb  = (bf16_t*)(ws + 16777216);
  bf16_t* xb   = (bf16_t*)(ws + 25165824);
  bf16_t* Qb   = (bf16_t*)(ws + 58720256);
  bf16_t* Kcal = (bf16_t*)(ws + 92274688);
  bf16_t* Vt   = (bf16_t*)(ws + 159383552);
  float*  Sc   = (float*)(ws + 226492416);
  bf16_t* Pb   = (bf16_t*)(ws + 25165824);
  const int PAIR = (ws_size >= 293601280ULL) ? 2 : 1;

  cast_f32_bf16<<<4096, 256, 0, stream>>>(Wq, wqb, 1048576);
  cast_f32_bf16<<<4096, 256, 0, stream>>>(Wk, wkb, 1048576);
  cast_f32_bf16<<<4096, 256, 0, stream>>>(Wv, wvb, 1048576);
  cast_f32_bf16<<<16384, 256, 0, stream>>>(x, xb, 4194304);
  cast_prepend_all<<<16384, 256, 0, stream>>>(cK, Kcal);
  transpose_f32_to_vt<<<dim3(64, 64, 4), dim3(32, 8), 0, stream>>>(
      cV, MB4, Vt, 8388608ULL, 2048);

  // all-batch Q/K/V projections; V written transposed straight into Vt
  gemm_qkv4<<<dim3(16, 64, 3), 256, 0, stream>>>(xb, wqb, wkb, wvb,
                                                 Qb, Kcal, Vt);

  // scores (PAIR-batched) + softmax into Pb
  for (int bp = 0; bp < 4; bp += PAIR) {
    gemm_bt4<<<dim3(32, 16, PAIR), 256, 0, stream>>>(
        Qb + (size_t)bp * MB4, MB4, 2048,
        Kcal + (size_t)bp * 8388608, 8388608ULL, 2048,
        Sc, 8388608ULL, 4096, 2048, inv_scale);
    for (int q = 0; q < PAIR; ++q)
      softmax_out<<<2048, 256, 0, stream>>>(
          Sc + (size_t)q * 8388608, Pb + (size_t)(bp + q) * 8388608);
  }

  // PV all-batch: out[b] = P[b] @ Vt[b]^T   (k=4096), 1024 blocks
  gemm_bt4<<<dim3(16, 16, 4), 256, 0, stream>>>(
      Pb, 8388608ULL, 4096, Vt, 8388608ULL, 4096,
      out, MB4, 2048, 4096, 1.0f);
}